// Round 1
// baseline (359.263 us; speedup 1.0000x reference)
//
#include <hip/hip_runtime.h>

// ---------- types ----------
typedef short bf8 __attribute__((ext_vector_type(8)));   // 8 bf16 bit-patterns (4 VGPR)
typedef short s4v __attribute__((ext_vector_type(4)));
typedef float f4  __attribute__((ext_vector_type(4)));

// Sizes (fixed for this problem)
// B=2, NT=16, LD=128 -> L=2048, M=B*L=4096, D=1024, H=16, Hd=64

__device__ __forceinline__ short f2b(float f) {          // fp32 -> bf16 (RNE)
    unsigned u = __float_as_uint(f);
    u += 0x7FFFu + ((u >> 16) & 1u);
    return (short)(u >> 16);
}

__device__ __forceinline__ f4 mfma16(bf8 a, bf8 b, f4 c) {
    return __builtin_amdgcn_mfma_f32_16x16x32_bf16(a, b, c, 0, 0, 0);
}

// ---------- fp32 -> bf16 bulk convert ----------
__global__ __launch_bounds__(256) void f2b_k(const float* __restrict__ src,
                                             short* __restrict__ dst, int n) {
    int i = (blockIdx.x * 256 + threadIdx.x) * 4;
    if (i >= n) return;
    const float4 v = *(const float4*)&src[i];
    s4v o;
    o[0] = f2b(v.x); o[1] = f2b(v.y); o[2] = f2b(v.z); o[3] = f2b(v.w);
    *(s4v*)&dst[i] = o;
}

// ---------- RoPE cos/sin table: [16 timesteps][32 freqs] ----------
__global__ void rope_tab_k(const int* __restrict__ dt,
                           float* __restrict__ ctab, float* __restrict__ stab) {
    const int t = threadIdx.x >> 5;   // 0..15
    const int i = threadIdx.x & 31;   // 0..31
    const float tv = (float)dt[t];
    const float invf = powf(100000.0f, -(float)i * (1.0f / 32.0f));
    const float a = tv * invf;
    ctab[t * 32 + i] = cosf(a);
    stab[t * 32 + i] = sinf(a);
}

// ---------- bf16 GEMM: C[4096x1024] = A @ W^T + bias, fused epilogues ----------
// MODE 0=Q (RoPE, *0.125, bf16 qrot (B,H,L,64))
// MODE 1=K (RoPE, fp32 k-out + bf16 k_b, both (B,H,L,64))
// MODE 2=V (fp32 v-out (B,H,L,64) + bf16 v_pack in PV-fragment order)
// MODE 3=O (fp32 out (M,1024))
template <int MODE>
__global__ __launch_bounds__(256) void gemm_k(
    const short* __restrict__ A, const short* __restrict__ W,
    const float* __restrict__ bias,
    float* __restrict__ outf, short* __restrict__ outb,
    const float* __restrict__ ctab, const float* __restrict__ stab) {
    __shared__ __align__(16) short As[128 * 40];  // +8 pad: 80 B rows, 16B-aligned
    __shared__ __align__(16) short Bs[128 * 40];

    const int n0 = blockIdx.x * 128;
    const int m0 = blockIdx.y * 128;
    const int tid = threadIdx.x;
    const int lane = tid & 63;
    const int w = tid >> 6;
    const int wr = w >> 1, wc = w & 1;           // wave -> 64x64 quadrant
    const int g = lane >> 4, cc = lane & 15;
    const int srow = tid >> 2;                    // staging: row 0..63 (+64)
    const int sq8 = (tid & 3) * 8;                // 16B quarter within 64B row-chunk

    f4 acc[4][4];
#pragma unroll
    for (int i = 0; i < 4; ++i)
#pragma unroll
        for (int j = 0; j < 4; ++j) acc[i][j] = (f4){0.f, 0.f, 0.f, 0.f};

    for (int k0 = 0; k0 < 1024; k0 += 32) {
        *(bf8*)&As[srow * 40 + sq8]        = *(const bf8*)&A[(m0 + srow) * 1024 + k0 + sq8];
        *(bf8*)&As[(srow + 64) * 40 + sq8] = *(const bf8*)&A[(m0 + srow + 64) * 1024 + k0 + sq8];
        *(bf8*)&Bs[srow * 40 + sq8]        = *(const bf8*)&W[(n0 + srow) * 1024 + k0 + sq8];
        *(bf8*)&Bs[(srow + 64) * 40 + sq8] = *(const bf8*)&W[(n0 + srow + 64) * 1024 + k0 + sq8];
        __syncthreads();
        bf8 af[4], bfr[4];
#pragma unroll
        for (int fm = 0; fm < 4; ++fm)
            af[fm] = *(const bf8*)&As[(64 * wr + 16 * fm + cc) * 40 + 8 * g];
#pragma unroll
        for (int fn = 0; fn < 4; ++fn)
            bfr[fn] = *(const bf8*)&Bs[(64 * wc + 16 * fn + cc) * 40 + 8 * g];
#pragma unroll
        for (int fm = 0; fm < 4; ++fm)
#pragma unroll
            for (int fn = 0; fn < 4; ++fn)
                acc[fm][fn] = mfma16(af[fm], bfr[fn], acc[fm][fn]);
        __syncthreads();
    }

    const int h = (n0 + 64 * wc) >> 6;  // head of this wave's 64-col quadrant
#pragma unroll
    for (int fm = 0; fm < 4; ++fm) {
#pragma unroll
        for (int r = 0; r < 4; ++r) {
            const int m = m0 + 64 * wr + 16 * fm + 4 * g + r;  // C row = 4g+reg
            const int b_ = m >> 11, l = m & 2047;
            if (MODE == 3) {
#pragma unroll
                for (int fn = 0; fn < 4; ++fn) {
                    const int n = n0 + 64 * wc + 16 * fn + cc;
                    outf[m * 1024 + n] = acc[fm][fn][r] + bias[n];
                }
            } else if (MODE == 2) {
                const int bh = b_ * 16 + h;
                const int st = l >> 5, s = l & 31;
                const int j = 4 * (s >> 4) + (s & 3);  // PV contraction slot
                const int g2 = (s >> 2) & 3;           // PV lane group
#pragma unroll
                for (int fn = 0; fn < 4; ++fn) {
                    const int d = 16 * fn + cc;
                    const int n = n0 + 64 * wc + 16 * fn + cc;
                    const float val = acc[fm][fn][r] + bias[n];
                    outf[(bh * 2048 + l) * 64 + d] = val;
                    const int vp = (((bh * 64 + st) * 4 + g2) * 4 + (d >> 4)) * 128 + (d & 15) * 8 + j;
                    outb[vp] = f2b(val);
                }
            } else {  // Q or K: RoPE pairs (fn, fn+2) = (d, d+32), same lane
                const int bh = b_ * 16 + h;
                const int tt = l >> 7;
#pragma unroll
                for (int fn = 0; fn < 2; ++fn) {
                    const int d1 = 16 * fn + cc;  // 0..31
                    const int n1 = n0 + 64 * wc + d1;
                    const float v1 = acc[fm][fn][r] + bias[n1];
                    const float v2 = acc[fm][fn + 2][r] + bias[n1 + 32];
                    const float ct = ctab[tt * 32 + d1];
                    const float sn = stab[tt * 32 + d1];
                    const float r1 = v1 * ct - v2 * sn;
                    const float r2 = v2 * ct + v1 * sn;
                    const int oi = (bh * 2048 + l) * 64 + d1;
                    if (MODE == 0) {
                        outb[oi]      = f2b(r1 * 0.125f);  // fold 1/sqrt(64) into q
                        outb[oi + 32] = f2b(r2 * 0.125f);
                    } else {
                        outf[oi] = r1; outf[oi + 32] = r2;
                        outb[oi] = f2b(r1); outb[oi + 32] = f2b(r2);
                    }
                }
            }
        }
    }
}

// ---------- flash attention, swapped-QK, 1 wave = 16 q-rows ----------
__global__ __launch_bounds__(256) void attn_k(
    const short* __restrict__ q_rot, const short* __restrict__ k_b,
    const short* __restrict__ v_pk, short* __restrict__ attn_b) {
    const int bh = blockIdx.x >> 5;     // (b*16+h)
    const int qc = blockIdx.x & 31;     // 64-row q chunk
    const int lane = threadIdx.x & 63;
    const int w = threadIdx.x >> 6;
    const int q0 = qc * 64 + w * 16;
    const int g = lane >> 4, cc = lane & 15;
    const int b_ = bh >> 4, h = bh & 15;

    const short* qp = q_rot + (bh * 2048 + q0) * 64;
    const bf8 qf0 = *(const bf8*)&qp[cc * 64 + 8 * g];        // B-frag: Q[q=cc][d=8g+j]
    const bf8 qf1 = *(const bf8*)&qp[cc * 64 + 32 + 8 * g];

    f4 O[4];
#pragma unroll
    for (int nb = 0; nb < 4; ++nb) O[nb] = (f4){0.f, 0.f, 0.f, 0.f};
    float mrun = -INFINITY, srun = 0.f;

    const short* kbase = k_b + bh * 131072;
    const short* vbase = v_pk + bh * 131072;

    for (int st = 0; st < 64; ++st) {
        const short* kp = kbase + st * 2048;  // 32 k-rows x 64
        const bf8 ka0 = *(const bf8*)&kp[cc * 64 + 8 * g];
        const bf8 ka1 = *(const bf8*)&kp[cc * 64 + 32 + 8 * g];
        const bf8 kb0 = *(const bf8*)&kp[(16 + cc) * 64 + 8 * g];
        const bf8 kb1 = *(const bf8*)&kp[(16 + cc) * 64 + 32 + 8 * g];
        f4 sA = (f4){0.f, 0.f, 0.f, 0.f};
        sA = mfma16(ka0, qf0, sA);
        sA = mfma16(ka1, qf1, sA);   // lane: S[q=cc][stored k-row 4g+r]
        f4 sB = (f4){0.f, 0.f, 0.f, 0.f};
        sB = mfma16(kb0, qf0, sB);
        sB = mfma16(kb1, qf1, sB);   // rows 16+4g+r

        float tm = fmaxf(fmaxf(fmaxf(sA[0], sA[1]), fmaxf(sA[2], sA[3])),
                         fmaxf(fmaxf(sB[0], sB[1]), fmaxf(sB[2], sB[3])));
        tm = fmaxf(tm, __shfl_xor(tm, 16));
        tm = fmaxf(tm, __shfl_xor(tm, 32));
        const float mnew = fmaxf(mrun, tm);
        const float corr = __expf(mrun - mnew);  // first iter: exp(-inf)=0
        float p[8];
        float ps = 0.f;
#pragma unroll
        for (int r = 0; r < 4; ++r) { p[r] = __expf(sA[r] - mnew); ps += p[r]; }
#pragma unroll
        for (int r = 0; r < 4; ++r) { p[4 + r] = __expf(sB[r] - mnew); ps += p[4 + r]; }
        ps += __shfl_xor(ps, 16);
        ps += __shfl_xor(ps, 32);
        srun = srun * corr + ps;
        mrun = mnew;

        bf8 pf;  // A-frag: P[q=cc][kk=8g+j]; tileA reg r -> j=r, tileB -> j=4+r
#pragma unroll
        for (int jj = 0; jj < 8; ++jj) pf[jj] = f2b(p[jj]);
#pragma unroll
        for (int r = 0; r < 4; ++r) {  // rescale O rows q=4g+r with that q's corr
            const float cr = __shfl(corr, 4 * g + r);
            O[0][r] *= cr; O[1][r] *= cr; O[2][r] *= cr; O[3][r] *= cr;
        }
        const short* vp = vbase + st * 2048 + g * 512 + cc * 8;
#pragma unroll
        for (int nb = 0; nb < 4; ++nb) {
            const bf8 vf = *(const bf8*)&vp[nb * 128];  // B-frag, pre-packed
            O[nb] = mfma16(pf, vf, O[nb]);
        }
    }
    const float inv = 1.0f / srun;
    float ir[4];
#pragma unroll
    for (int r = 0; r < 4; ++r) ir[r] = __shfl(inv, 4 * g + r);
#pragma unroll
    for (int nb = 0; nb < 4; ++nb)
#pragma unroll
        for (int r = 0; r < 4; ++r)
            attn_b[(b_ * 2048 + q0 + 4 * g + r) * 1024 + h * 64 + 16 * nb + cc] =
                f2b(O[nb][r] * ir[r]);
}

// ---------- launch ----------
extern "C" void kernel_launch(void* const* d_in, const int* in_sizes, int n_in,
                              void* d_out, int out_size, void* d_ws, size_t ws_size,
                              hipStream_t stream) {
    const float* x  = (const float*)d_in[0];
    const int*   dt = (const int*)d_in[1];
    const float* Wq = (const float*)d_in[2];
    const float* bq = (const float*)d_in[3];
    const float* Wk = (const float*)d_in[4];
    const float* bk = (const float*)d_in[5];
    const float* Wv = (const float*)d_in[6];
    const float* bv = (const float*)d_in[7];
    const float* Wo = (const float*)d_in[8];
    const float* bo = (const float*)d_in[9];

    float* out   = (float*)d_out;          // (B,NT,LD,D) = (M,1024)
    float* out_k = out + 4194304;          // (B,H,L,64)
    float* out_v = out + 8388608;          // (B,H,L,64)

    short* xb   = (short*)d_ws;            // bf16 x           4M
    short* wqb  = xb + 4194304;            // bf16 weights     1M each
    short* wkb  = wqb + 1048576;
    short* wvb  = wkb + 1048576;
    short* wob  = wvb + 1048576;
    short* qrot = wob + 1048576;           // q*0.125 rotated, (B,H,L,64)
    short* kbb  = qrot + 4194304;          // k rotated bf16,  (B,H,L,64)
    short* vpk  = kbb + 4194304;           // v packed for PV frags
    short* atb  = vpk + 4194304;           // attention output (B,L,1024) bf16
    float* ctab = (float*)(atb + 4194304); // 16x32
    float* stab = ctab + 512;

    f2b_k<<<4096, 256, 0, stream>>>(x, xb, 4194304);
    f2b_k<<<1024, 256, 0, stream>>>(Wq, wqb, 1048576);
    f2b_k<<<1024, 256, 0, stream>>>(Wk, wkb, 1048576);
    f2b_k<<<1024, 256, 0, stream>>>(Wv, wvb, 1048576);
    f2b_k<<<1024, 256, 0, stream>>>(Wo, wob, 1048576);
    rope_tab_k<<<1, 512, 0, stream>>>(dt, ctab, stab);

    dim3 gg(8, 32);  // (N/128, M/128)
    gemm_k<0><<<gg, 256, 0, stream>>>(xb, wqb, bq, nullptr, qrot, ctab, stab);
    gemm_k<1><<<gg, 256, 0, stream>>>(xb, wkb, bk, out_k, kbb, ctab, stab);
    gemm_k<2><<<gg, 256, 0, stream>>>(xb, wvb, bv, out_v, vpk, ctab, stab);
    attn_k<<<1024, 256, 0, stream>>>(qrot, kbb, vpk, atb);
    gemm_k<3><<<gg, 256, 0, stream>>>(atb, wob, bo, out, nullptr, ctab, stab);
}

// Round 2
// 314.431 us; speedup vs baseline: 1.1426x; 1.1426x over previous
//
#include <hip/hip_runtime.h>

// ---------- types ----------
typedef short bf8 __attribute__((ext_vector_type(8)));   // 8 bf16 bit-patterns (4 VGPR)
typedef short s4v __attribute__((ext_vector_type(4)));
typedef float f4  __attribute__((ext_vector_type(4)));

// Sizes fixed: B=2, NT=16, LD=128 -> L=2048, M=4096, D=1024, H=16, Hd=64

__device__ __forceinline__ short f2b(float f) {          // fp32 -> bf16 (RNE)
    unsigned u = __float_as_uint(f);
    u += 0x7FFFu + ((u >> 16) & 1u);
    return (short)(u >> 16);
}

__device__ __forceinline__ f4 mfma16(bf8 a, bf8 b, f4 c) {
    return __builtin_amdgcn_mfma_f32_16x16x32_bf16(a, b, c, 0, 0, 0);
}

__device__ __forceinline__ void gl_lds16(const short* g, short* l) {
    __builtin_amdgcn_global_load_lds(
        (const __attribute__((address_space(1))) void*)g,
        (__attribute__((address_space(3))) void*)l, 16, 0, 0);
}

// ---------- fp32 -> bf16 bulk convert ----------
__global__ __launch_bounds__(256) void f2b_k(const float* __restrict__ src,
                                             short* __restrict__ dst, int n) {
    int i = (blockIdx.x * 256 + threadIdx.x) * 4;
    if (i >= n) return;
    const float4 v = *(const float4*)&src[i];
    s4v o;
    o[0] = f2b(v.x); o[1] = f2b(v.y); o[2] = f2b(v.z); o[3] = f2b(v.w);
    *(s4v*)&dst[i] = o;
}

// ---------- RoPE cos/sin table: [16 timesteps][32 freqs] ----------
__global__ void rope_tab_k(const int* __restrict__ dt,
                           float* __restrict__ ctab, float* __restrict__ stab) {
    const int t = threadIdx.x >> 5;   // 0..15
    const int i = threadIdx.x & 31;   // 0..31
    const float tv = (float)dt[t];
    const float invf = powf(100000.0f, -(float)i * (1.0f / 32.0f));
    const float a = tv * invf;
    ctab[t * 32 + i] = cosf(a);
    stab[t * 32 + i] = sinf(a);
}

// ---------- fused QKV GEMM: C[4096 x 3072] = x @ [Wq;Wk;Wv]^T + b, fused epilogues ----------
// third 0 = Q (RoPE, *0.125 -> bf16 qrot), 1 = K (RoPE -> fp32 out_k + bf16 kbb),
// third 2 = V (fp32 out_v + bf16 vpk in PV-fragment order)
__global__ __launch_bounds__(256) void gemm_qkv_k(
    const short* __restrict__ A, const short* __restrict__ W,
    const float* __restrict__ bq, const float* __restrict__ bk, const float* __restrict__ bv,
    float* __restrict__ out_k, float* __restrict__ out_v,
    short* __restrict__ qrot, short* __restrict__ kbb, short* __restrict__ vpk,
    const float* __restrict__ ctab, const float* __restrict__ stab) {
    __shared__ __align__(16) short As[128 * 32];   // linear, for global_load_lds
    __shared__ __align__(16) short Bs[128 * 32];

    const int n0f = blockIdx.x * 128;              // 0..2944
    const int m0 = blockIdx.y * 128;
    const int tid = threadIdx.x;
    const int lane = tid & 63;
    const int w = tid >> 6;
    const int wr = w >> 1, wc = w & 1;
    const int g = lane >> 4, cc = lane & 15;

    // staging: chunk c = w*128 + lane (16B chunks); row = c>>2, part = (c&3)*8
    const int c0 = w * 128 + lane;
    const int ar0 = c0 >> 2, ap0 = (c0 & 3) * 8;
    const short* Ag0 = A + (m0 + ar0) * 1024 + ap0;
    const short* Ag1 = Ag0 + 16 * 1024;
    const short* Wg0 = W + (n0f + ar0) * 1024 + ap0;
    const short* Wg1 = Wg0 + 16 * 1024;
    short* lA0 = &As[w * 1024];
    short* lA1 = &As[w * 1024 + 512];
    short* lB0 = &Bs[w * 1024];
    short* lB1 = &Bs[w * 1024 + 512];

    f4 acc[4][4];
#pragma unroll
    for (int i = 0; i < 4; ++i)
#pragma unroll
        for (int j = 0; j < 4; ++j) acc[i][j] = (f4){0.f, 0.f, 0.f, 0.f};

    for (int k0 = 0; k0 < 1024; k0 += 32) {
        gl_lds16(Ag0 + k0, lA0);
        gl_lds16(Ag1 + k0, lA1);
        gl_lds16(Wg0 + k0, lB0);
        gl_lds16(Wg1 + k0, lB1);
        __syncthreads();
        bf8 af[4], bfr[4];
#pragma unroll
        for (int fm = 0; fm < 4; ++fm)
            af[fm] = *(const bf8*)&As[(64 * wr + 16 * fm + cc) * 32 + 8 * g];
#pragma unroll
        for (int fn = 0; fn < 4; ++fn)
            bfr[fn] = *(const bf8*)&Bs[(64 * wc + 16 * fn + cc) * 32 + 8 * g];
#pragma unroll
        for (int fm = 0; fm < 4; ++fm)
#pragma unroll
            for (int fn = 0; fn < 4; ++fn)
                acc[fm][fn] = mfma16(af[fm], bfr[fn], acc[fm][fn]);
        __syncthreads();
    }

    const int third = n0f >> 10;
    const int n0 = n0f & 1023;
    const int h = (n0 + 64 * wc) >> 6;
    const float* bias = (third == 0) ? bq : ((third == 1) ? bk : bv);

#pragma unroll
    for (int fm = 0; fm < 4; ++fm) {
#pragma unroll
        for (int r = 0; r < 4; ++r) {
            const int m = m0 + 64 * wr + 16 * fm + 4 * g + r;
            const int b_ = m >> 11, l = m & 2047;
            const int bh2 = b_ * 16 + h;
            if (third == 2) {   // V: fp32 out + PV-fragment pack
                const int st2 = l >> 5, s = l & 31;
                const int j = 4 * (s >> 4) + (s & 3);
                const int g2 = (s >> 2) & 3;
#pragma unroll
                for (int fn = 0; fn < 4; ++fn) {
                    const int d = 16 * fn + cc;
                    const int n = n0 + 64 * wc + 16 * fn + cc;
                    const float val = acc[fm][fn][r] + bias[n];
                    out_v[(bh2 * 2048 + l) * 64 + d] = val;
                    const int vp = (((bh2 * 64 + st2) * 4 + g2) * 4 + (d >> 4)) * 128 + (d & 15) * 8 + j;
                    vpk[vp] = f2b(val);
                }
            } else {            // Q or K: RoPE pairs (fn, fn+2) = (d, d+32), same lane
                const int tt = l >> 7;
#pragma unroll
                for (int fn = 0; fn < 2; ++fn) {
                    const int d1 = 16 * fn + cc;
                    const int n1 = n0 + 64 * wc + d1;
                    const float v1 = acc[fm][fn][r] + bias[n1];
                    const float v2 = acc[fm][fn + 2][r] + bias[n1 + 32];
                    const float ct = ctab[tt * 32 + d1];
                    const float sn = stab[tt * 32 + d1];
                    const float r1 = v1 * ct - v2 * sn;
                    const float r2 = v2 * ct + v1 * sn;
                    const int oi = (bh2 * 2048 + l) * 64 + d1;
                    if (third == 0) {
                        qrot[oi]      = f2b(r1 * 0.125f);   // fold 1/sqrt(64)
                        qrot[oi + 32] = f2b(r2 * 0.125f);
                    } else {
                        out_k[oi] = r1; out_k[oi + 32] = r2;
                        kbb[oi] = f2b(r1); kbb[oi + 32] = f2b(r2);
                    }
                }
            }
        }
    }
}

// ---------- Wo GEMM: out[4096x1024] = atb @ Wo^T + bo ; BM=128 BN=64 -> 512 blocks ----------
__global__ __launch_bounds__(256) void gemm_o_k(
    const short* __restrict__ A, const short* __restrict__ W,
    const float* __restrict__ bias, float* __restrict__ out) {
    __shared__ __align__(16) short As[128 * 32];
    __shared__ __align__(16) short Bs[64 * 32];

    const int n0 = blockIdx.x * 64;
    const int m0 = blockIdx.y * 128;
    const int tid = threadIdx.x;
    const int lane = tid & 63;
    const int w = tid >> 6;
    const int wr = w >> 1, wc = w & 1;   // wave tile: 64 x 32
    const int g = lane >> 4, cc = lane & 15;

    const int c0 = w * 128 + lane;
    const int ar0 = c0 >> 2, ap0 = (c0 & 3) * 8;
    const short* Ag0 = A + (m0 + ar0) * 1024 + ap0;
    const short* Ag1 = Ag0 + 16 * 1024;
    const int cb = w * 64 + lane;
    const short* Wg0 = W + (n0 + (cb >> 2)) * 1024 + (cb & 3) * 8;
    short* lA0 = &As[w * 1024];
    short* lA1 = &As[w * 1024 + 512];
    short* lB0 = &Bs[w * 512];

    f4 acc[4][2];
#pragma unroll
    for (int i = 0; i < 4; ++i) { acc[i][0] = (f4){0,0,0,0}; acc[i][1] = (f4){0,0,0,0}; }

    for (int k0 = 0; k0 < 1024; k0 += 32) {
        gl_lds16(Ag0 + k0, lA0);
        gl_lds16(Ag1 + k0, lA1);
        gl_lds16(Wg0 + k0, lB0);
        __syncthreads();
        bf8 af[4], bfr[2];
#pragma unroll
        for (int fm = 0; fm < 4; ++fm)
            af[fm] = *(const bf8*)&As[(64 * wr + 16 * fm + cc) * 32 + 8 * g];
#pragma unroll
        for (int fn = 0; fn < 2; ++fn)
            bfr[fn] = *(const bf8*)&Bs[(32 * wc + 16 * fn + cc) * 32 + 8 * g];
#pragma unroll
        for (int fm = 0; fm < 4; ++fm)
#pragma unroll
            for (int fn = 0; fn < 2; ++fn)
                acc[fm][fn] = mfma16(af[fm], bfr[fn], acc[fm][fn]);
        __syncthreads();
    }
#pragma unroll
    for (int fm = 0; fm < 4; ++fm)
#pragma unroll
        for (int r = 0; r < 4; ++r) {
            const int m = m0 + 64 * wr + 16 * fm + 4 * g + r;
#pragma unroll
            for (int fn = 0; fn < 2; ++fn) {
                const int n = n0 + 32 * wc + 16 * fn + cc;
                out[m * 1024 + n] = acc[fm][fn][r] + bias[n];
            }
        }
}

// ---------- flash attention: XCD swizzle + reg prefetch + defer-max ----------
__global__ __launch_bounds__(256) void attn_k(
    const short* __restrict__ q_rot, const short* __restrict__ k_b,
    const short* __restrict__ v_pk, short* __restrict__ attn_b) {
    // XCD-aware decode: 4 bh per XCD -> K/V working set 2MB fits per-XCD L2
    const int i = blockIdx.x;
    const int xcd = i & 7, slot = i >> 3;
    const int bh = xcd + 8 * (slot & 3);
    const int qc = slot >> 2;
    const int lane = threadIdx.x & 63;
    const int w = threadIdx.x >> 6;
    const int q0 = qc * 64 + w * 16;
    const int g = lane >> 4, cc = lane & 15;
    const int b_ = bh >> 4, h = bh & 15;

    const short* qp = q_rot + (bh * 2048 + q0) * 64;
    const bf8 qf0 = *(const bf8*)&qp[cc * 64 + 8 * g];
    const bf8 qf1 = *(const bf8*)&qp[cc * 64 + 32 + 8 * g];

    f4 O[4];
#pragma unroll
    for (int nb = 0; nb < 4; ++nb) O[nb] = (f4){0.f, 0.f, 0.f, 0.f};
    float mrun = -INFINITY, srun = 0.f;

    const short* kbase = k_b + bh * 131072;
    const short* vbase = v_pk + bh * 131072;

    // prologue: tile 0 into registers
    bf8 ka0 = *(const bf8*)&kbase[cc * 64 + 8 * g];
    bf8 ka1 = *(const bf8*)&kbase[cc * 64 + 32 + 8 * g];
    bf8 kb0 = *(const bf8*)&kbase[(16 + cc) * 64 + 8 * g];
    bf8 kb1 = *(const bf8*)&kbase[(16 + cc) * 64 + 32 + 8 * g];
    const short* vp0 = vbase + g * 512 + cc * 8;
    bf8 vv0 = *(const bf8*)&vp0[0];
    bf8 vv1 = *(const bf8*)&vp0[128];
    bf8 vv2 = *(const bf8*)&vp0[256];
    bf8 vv3 = *(const bf8*)&vp0[384];

    for (int st = 0; st < 64; ++st) {
        // prefetch next tile (wraps at end; redundant load of tile 0 is harmless)
        const int sn = (st + 1) & 63;
        const short* kn = kbase + sn * 2048;
        const bf8 nka0 = *(const bf8*)&kn[cc * 64 + 8 * g];
        const bf8 nka1 = *(const bf8*)&kn[cc * 64 + 32 + 8 * g];
        const bf8 nkb0 = *(const bf8*)&kn[(16 + cc) * 64 + 8 * g];
        const bf8 nkb1 = *(const bf8*)&kn[(16 + cc) * 64 + 32 + 8 * g];
        const short* vn = vbase + sn * 2048 + g * 512 + cc * 8;
        const bf8 nv0 = *(const bf8*)&vn[0];
        const bf8 nv1 = *(const bf8*)&vn[128];
        const bf8 nv2 = *(const bf8*)&vn[256];
        const bf8 nv3 = *(const bf8*)&vn[384];

        f4 sA = (f4){0.f, 0.f, 0.f, 0.f};
        sA = mfma16(ka0, qf0, sA);
        sA = mfma16(ka1, qf1, sA);    // lane: S[q=cc][k-row 4g+r]
        f4 sB = (f4){0.f, 0.f, 0.f, 0.f};
        sB = mfma16(kb0, qf0, sB);
        sB = mfma16(kb1, qf1, sB);    // rows 16+4g+r

        float tm = fmaxf(fmaxf(fmaxf(sA[0], sA[1]), fmaxf(sA[2], sA[3])),
                         fmaxf(fmaxf(sB[0], sB[1]), fmaxf(sB[2], sB[3])));
        tm = fmaxf(tm, __shfl_xor(tm, 16));
        tm = fmaxf(tm, __shfl_xor(tm, 32));   // per-q (cc) max, uniform across g

        if (!__all(tm <= mrun + 8.f)) {       // defer-max: rescale only on real growth
            const float mnew = fmaxf(mrun, tm);
            const float corr = __expf(mrun - mnew);
            srun *= corr;                      // srun is per-cc uniform
#pragma unroll
            for (int r = 0; r < 4; ++r) {      // O rows are q=4g+r -> need that q's corr
                const float cr = __shfl(corr, 4 * g + r);
                O[0][r] *= cr; O[1][r] *= cr; O[2][r] *= cr; O[3][r] *= cr;
            }
            mrun = mnew;
        }

        float p[8];
        float ps = 0.f;
#pragma unroll
        for (int r = 0; r < 4; ++r) { p[r] = __expf(sA[r] - mrun); ps += p[r]; }
#pragma unroll
        for (int r = 0; r < 4; ++r) { p[4 + r] = __expf(sB[r] - mrun); ps += p[4 + r]; }
        ps += __shfl_xor(ps, 16);
        ps += __shfl_xor(ps, 32);
        srun += ps;

        bf8 pf;
#pragma unroll
        for (int jj = 0; jj < 8; ++jj) pf[jj] = f2b(p[jj]);
        O[0] = mfma16(pf, vv0, O[0]);
        O[1] = mfma16(pf, vv1, O[1]);
        O[2] = mfma16(pf, vv2, O[2]);
        O[3] = mfma16(pf, vv3, O[3]);

        ka0 = nka0; ka1 = nka1; kb0 = nkb0; kb1 = nkb1;
        vv0 = nv0; vv1 = nv1; vv2 = nv2; vv3 = nv3;
    }
    const float inv = 1.0f / srun;
    float ir[4];
#pragma unroll
    for (int r = 0; r < 4; ++r) ir[r] = __shfl(inv, 4 * g + r);
#pragma unroll
    for (int nb = 0; nb < 4; ++nb)
#pragma unroll
        for (int r = 0; r < 4; ++r)
            attn_b[(b_ * 2048 + q0 + 4 * g + r) * 1024 + h * 64 + 16 * nb + cc] =
                f2b(O[nb][r] * ir[r]);
}

// ---------- launch ----------
extern "C" void kernel_launch(void* const* d_in, const int* in_sizes, int n_in,
                              void* d_out, int out_size, void* d_ws, size_t ws_size,
                              hipStream_t stream) {
    const float* x  = (const float*)d_in[0];
    const int*   dt = (const int*)d_in[1];
    const float* Wq = (const float*)d_in[2];
    const float* bq = (const float*)d_in[3];
    const float* Wk = (const float*)d_in[4];
    const float* bk = (const float*)d_in[5];
    const float* Wv = (const float*)d_in[6];
    const float* bv = (const float*)d_in[7];
    const float* Wo = (const float*)d_in[8];
    const float* bo = (const float*)d_in[9];

    float* out   = (float*)d_out;          // (M,1024)
    float* out_k = out + 4194304;          // (B,H,L,64)
    float* out_v = out + 8388608;

    short* xb   = (short*)d_ws;            // bf16 x
    short* wqb  = xb + 4194304;            // stacked [Wq;Wk;Wv] bf16 (contiguous)
    short* wkb  = wqb + 1048576;
    short* wvb  = wkb + 1048576;
    short* wob  = wvb + 1048576;
    short* qrot = wob + 1048576;
    short* kbb  = qrot + 4194304;
    short* vpk  = kbb + 4194304;
    short* atb  = vpk + 4194304;
    float* ctab = (float*)(atb + 4194304);
    float* stab = ctab + 512;

    f2b_k<<<4096, 256, 0, stream>>>(x, xb, 4194304);
    f2b_k<<<1024, 256, 0, stream>>>(Wq, wqb, 1048576);
    f2b_k<<<1024, 256, 0, stream>>>(Wk, wkb, 1048576);
    f2b_k<<<1024, 256, 0, stream>>>(Wv, wvb, 1048576);
    f2b_k<<<1024, 256, 0, stream>>>(Wo, wob, 1048576);
    rope_tab_k<<<1, 512, 0, stream>>>(dt, ctab, stab);

    gemm_qkv_k<<<dim3(24, 32), 256, 0, stream>>>(xb, wqb, bq, bk, bv,
                                                 out_k, out_v, qrot, kbb, vpk, ctab, stab);
    attn_k<<<1024, 256, 0, stream>>>(qrot, kbb, vpk, atb);
    gemm_o_k<<<dim3(16, 32), 256, 0, stream>>>(atb, wob, bo, out);
}

// Round 3
// 307.883 us; speedup vs baseline: 1.1669x; 1.0213x over previous
//
#include <hip/hip_runtime.h>

// ---------- types ----------
typedef short bf8 __attribute__((ext_vector_type(8)));   // 8 bf16 bit-patterns (4 VGPR)
typedef short s4v __attribute__((ext_vector_type(4)));
typedef float f4  __attribute__((ext_vector_type(4)));

// Sizes fixed: B=2, NT=16, LD=128 -> L=2048, M=4096, D=1024, H=16, Hd=64

__device__ __forceinline__ short f2b(float f) {          // fp32 -> bf16 (RNE)
    unsigned u = __float_as_uint(f);
    u += 0x7FFFu + ((u >> 16) & 1u);
    return (short)(u >> 16);
}
__device__ __forceinline__ float b2f(short s) {
    return __uint_as_float(((unsigned)(unsigned short)s) << 16);
}

__device__ __forceinline__ f4 mfma16(bf8 a, bf8 b, f4 c) {
    return __builtin_amdgcn_mfma_f32_16x16x32_bf16(a, b, c, 0, 0, 0);
}

__device__ __forceinline__ void gl_lds16(const short* g, short* l) {
    __builtin_amdgcn_global_load_lds(
        (const __attribute__((address_space(1))) void*)g,
        (__attribute__((address_space(3))) void*)l, 16, 0, 0);
}

#define EXP2F(x) __builtin_amdgcn_exp2f(x)

// ---------- fused converts: x + 4 weights -> bf16, plus RoPE table ----------
__global__ __launch_bounds__(256) void conv_k(
    const float* __restrict__ x, const float* __restrict__ wq,
    const float* __restrict__ wk, const float* __restrict__ wv,
    const float* __restrict__ wo, const int* __restrict__ dt,
    short* __restrict__ xb, short* __restrict__ wqb, short* __restrict__ wkb,
    short* __restrict__ wvb, short* __restrict__ wob,
    float* __restrict__ ctab, float* __restrict__ stab) {
    if (blockIdx.x == 8192) {   // RoPE cos/sin table: [16 t][32 freqs]
        const int tid = threadIdx.x;
        const int ii = tid & 31;
        const float invf = exp2f(-(float)ii * (16.609640474436812f / 32.f)); // 1e5^(-i/32)
        for (int t = tid >> 5; t < 16; t += 8) {
            const float a = (float)dt[t] * invf;
            ctab[t * 32 + ii] = cosf(a);
            stab[t * 32 + ii] = sinf(a);
        }
        return;
    }
    int idx = (blockIdx.x * 256 + threadIdx.x) * 4;
    const float* s; short* d; int off = idx;
    if (idx < 4194304)      { s = x;  d = xb; }
    else if (idx < 5242880) { s = wq; d = wqb; off = idx - 4194304; }
    else if (idx < 6291456) { s = wk; d = wkb; off = idx - 5242880; }
    else if (idx < 7340032) { s = wv; d = wvb; off = idx - 6291456; }
    else                    { s = wo; d = wob; off = idx - 7340032; }
    const float4 v = *(const float4*)&s[off];
    s4v o;
    o[0] = f2b(v.x); o[1] = f2b(v.y); o[2] = f2b(v.z); o[3] = f2b(v.w);
    *(s4v*)&d[off] = o;
}

// ---------- fused QKV GEMM: C[4096 x 3072] = x @ [Wq;Wk;Wv]^T + b, fused epilogues ----------
// third 0 = Q (RoPE, *0.125*log2e -> bf16 qrot), 1 = K (RoPE -> fp32 out_k + bf16 kbb),
// third 2 = V (fp32 out_v + bf16 vpk in PV-fragment order)
__global__ __launch_bounds__(256) void gemm_qkv_k(
    const short* __restrict__ A, const short* __restrict__ W,
    const float* __restrict__ bq, const float* __restrict__ bk, const float* __restrict__ bv,
    float* __restrict__ out_k, float* __restrict__ out_v,
    short* __restrict__ qrot, short* __restrict__ kbb, short* __restrict__ vpk,
    const float* __restrict__ ctab, const float* __restrict__ stab) {
    __shared__ __align__(16) short As[128 * 32];   // linear, for global_load_lds
    __shared__ __align__(16) short Bs[128 * 32];

    const int n0f = blockIdx.x * 128;              // 0..2944
    const int m0 = blockIdx.y * 128;
    const int tid = threadIdx.x;
    const int lane = tid & 63;
    const int w = tid >> 6;
    const int wr = w >> 1, wc = w & 1;
    const int g = lane >> 4, cc = lane & 15;

    const int c0 = w * 128 + lane;
    const int ar0 = c0 >> 2, ap0 = (c0 & 3) * 8;
    const short* Ag0 = A + (m0 + ar0) * 1024 + ap0;
    const short* Ag1 = Ag0 + 16 * 1024;
    const short* Wg0 = W + (n0f + ar0) * 1024 + ap0;
    const short* Wg1 = Wg0 + 16 * 1024;
    short* lA0 = &As[w * 1024];
    short* lA1 = &As[w * 1024 + 512];
    short* lB0 = &Bs[w * 1024];
    short* lB1 = &Bs[w * 1024 + 512];

    f4 acc[4][4];
#pragma unroll
    for (int i = 0; i < 4; ++i)
#pragma unroll
        for (int j = 0; j < 4; ++j) acc[i][j] = (f4){0.f, 0.f, 0.f, 0.f};

    for (int k0 = 0; k0 < 1024; k0 += 32) {
        gl_lds16(Ag0 + k0, lA0);
        gl_lds16(Ag1 + k0, lA1);
        gl_lds16(Wg0 + k0, lB0);
        gl_lds16(Wg1 + k0, lB1);
        __syncthreads();
        bf8 af[4], bfr[4];
#pragma unroll
        for (int fm = 0; fm < 4; ++fm)
            af[fm] = *(const bf8*)&As[(64 * wr + 16 * fm + cc) * 32 + 8 * g];
#pragma unroll
        for (int fn = 0; fn < 4; ++fn)
            bfr[fn] = *(const bf8*)&Bs[(64 * wc + 16 * fn + cc) * 32 + 8 * g];
#pragma unroll
        for (int fm = 0; fm < 4; ++fm)
#pragma unroll
            for (int fn = 0; fn < 4; ++fn)
                acc[fm][fn] = mfma16(af[fm], bfr[fn], acc[fm][fn]);
        __syncthreads();
    }

    const int third = n0f >> 10;
    const int n0 = n0f & 1023;
    const int h = (n0 + 64 * wc) >> 6;
    const float* bias = (third == 0) ? bq : ((third == 1) ? bk : bv);

#pragma unroll
    for (int fm = 0; fm < 4; ++fm) {
#pragma unroll
        for (int r = 0; r < 4; ++r) {
            const int m = m0 + 64 * wr + 16 * fm + 4 * g + r;
            const int b_ = m >> 11, l = m & 2047;
            const int bh2 = b_ * 16 + h;
            if (third == 2) {   // V: fp32 out + PV-fragment pack
                const int st2 = l >> 5, s = l & 31;
                const int j = 4 * (s >> 4) + (s & 3);
                const int g2 = (s >> 2) & 3;
#pragma unroll
                for (int fn = 0; fn < 4; ++fn) {
                    const int d = 16 * fn + cc;
                    const int n = n0 + 64 * wc + 16 * fn + cc;
                    const float val = acc[fm][fn][r] + bias[n];
                    out_v[(bh2 * 2048 + l) * 64 + d] = val;
                    const int vp = (((bh2 * 64 + st2) * 4 + g2) * 4 + (d >> 4)) * 128 + (d & 15) * 8 + j;
                    vpk[vp] = f2b(val);
                }
            } else {            // Q or K: RoPE pairs (fn, fn+2) = (d, d+32), same lane
                const int tt = l >> 7;
#pragma unroll
                for (int fn = 0; fn < 2; ++fn) {
                    const int d1 = 16 * fn + cc;
                    const int n1 = n0 + 64 * wc + d1;
                    const float v1 = acc[fm][fn][r] + bias[n1];
                    const float v2 = acc[fm][fn + 2][r] + bias[n1 + 32];
                    const float ct = ctab[tt * 32 + d1];
                    const float sn = stab[tt * 32 + d1];
                    const float r1 = v1 * ct - v2 * sn;
                    const float r2 = v2 * ct + v1 * sn;
                    const int oi = (bh2 * 2048 + l) * 64 + d1;
                    if (third == 0) {
                        // fold 1/sqrt(64) * log2(e): softmax runs in exp2 domain
                        qrot[oi]      = f2b(r1 * 0.18033688011f);
                        qrot[oi + 32] = f2b(r2 * 0.18033688011f);
                    } else {
                        out_k[oi] = r1; out_k[oi + 32] = r2;
                        kbb[oi] = f2b(r1); kbb[oi + 32] = f2b(r2);
                    }
                }
            }
        }
    }
}

// ---------- Wo GEMM: out[4096x1024] = atb @ Wo^T + bo ; BM=128 BN=64 ----------
__global__ __launch_bounds__(256) void gemm_o_k(
    const short* __restrict__ A, const short* __restrict__ W,
    const float* __restrict__ bias, float* __restrict__ out) {
    __shared__ __align__(16) short As[128 * 32];
    __shared__ __align__(16) short Bs[64 * 32];

    const int n0 = blockIdx.x * 64;
    const int m0 = blockIdx.y * 128;
    const int tid = threadIdx.x;
    const int lane = tid & 63;
    const int w = tid >> 6;
    const int wr = w >> 1, wc = w & 1;   // wave tile: 64 x 32
    const int g = lane >> 4, cc = lane & 15;

    const int c0 = w * 128 + lane;
    const int ar0 = c0 >> 2, ap0 = (c0 & 3) * 8;
    const short* Ag0 = A + (m0 + ar0) * 1024 + ap0;
    const short* Ag1 = Ag0 + 16 * 1024;
    const int cb = w * 64 + lane;
    const short* Wg0 = W + (n0 + (cb >> 2)) * 1024 + (cb & 3) * 8;
    short* lA0 = &As[w * 1024];
    short* lA1 = &As[w * 1024 + 512];
    short* lB0 = &Bs[w * 512];

    f4 acc[4][2];
#pragma unroll
    for (int i = 0; i < 4; ++i) { acc[i][0] = (f4){0,0,0,0}; acc[i][1] = (f4){0,0,0,0}; }

    for (int k0 = 0; k0 < 1024; k0 += 32) {
        gl_lds16(Ag0 + k0, lA0);
        gl_lds16(Ag1 + k0, lA1);
        gl_lds16(Wg0 + k0, lB0);
        __syncthreads();
        bf8 af[4], bfr[2];
#pragma unroll
        for (int fm = 0; fm < 4; ++fm)
            af[fm] = *(const bf8*)&As[(64 * wr + 16 * fm + cc) * 32 + 8 * g];
#pragma unroll
        for (int fn = 0; fn < 2; ++fn)
            bfr[fn] = *(const bf8*)&Bs[(32 * wc + 16 * fn + cc) * 32 + 8 * g];
#pragma unroll
        for (int fm = 0; fm < 4; ++fm)
#pragma unroll
            for (int fn = 0; fn < 2; ++fn)
                acc[fm][fn] = mfma16(af[fm], bfr[fn], acc[fm][fn]);
        __syncthreads();
    }
#pragma unroll
    for (int fm = 0; fm < 4; ++fm)
#pragma unroll
        for (int r = 0; r < 4; ++r) {
            const int m = m0 + 64 * wr + 16 * fm + 4 * g + r;
#pragma unroll
            for (int fn = 0; fn < 2; ++fn) {
                const int n = n0 + 32 * wc + 16 * fn + cc;
                out[m * 1024 + n] = acc[fm][fn][r] + bias[n];
            }
        }
}

// ---------- flash attention, swapped-QK, split-K option ----------
// SPLIT=1: 2048 blocks (bh x qc x kh), writes unnormalized O + (m,s) partials.
// SPLIT=0: 1024 blocks, writes normalized atb directly.
template <int SPLIT>
__global__ __launch_bounds__(256) void attn_k(
    const short* __restrict__ q_rot, const short* __restrict__ k_b,
    const short* __restrict__ v_pk, short* __restrict__ atb,
    short* __restrict__ opart, float2* __restrict__ ms) {
    const int i = blockIdx.x;
    const int xcd = i & 7, slot = i >> 3;          // 4 bh per XCD -> K/V fits per-XCD L2
    const int bh = xcd + 8 * (slot & 3);
    const int r2 = slot >> 2;
    const int qc = SPLIT ? (r2 & 31) : r2;
    const int kh = SPLIT ? (r2 >> 5) : 0;
    const int lane = threadIdx.x & 63;
    const int w = threadIdx.x >> 6;
    const int q0 = qc * 64 + w * 16;
    const int g = lane >> 4, cc = lane & 15;
    const int NT = SPLIT ? 32 : 64;

    const short* qp = q_rot + (bh * 2048 + q0) * 64;
    const bf8 qf0 = *(const bf8*)&qp[cc * 64 + 8 * g];
    const bf8 qf1 = *(const bf8*)&qp[cc * 64 + 32 + 8 * g];

    f4 O[4];
#pragma unroll
    for (int nb = 0; nb < 4; ++nb) O[nb] = (f4){0.f, 0.f, 0.f, 0.f};
    float mrun = -INFINITY;   // per-q (cc) uniform, log2 domain
    float sl = 0.f;           // per-LANE partial sum (reduced at end)

    const short* kbase = k_b + bh * 131072 + kh * 65536;
    const short* vbase = v_pk + bh * 131072 + kh * 65536;

    // prologue: tile 0 into registers
    bf8 ka0 = *(const bf8*)&kbase[cc * 64 + 8 * g];
    bf8 ka1 = *(const bf8*)&kbase[cc * 64 + 32 + 8 * g];
    bf8 kb0 = *(const bf8*)&kbase[(16 + cc) * 64 + 8 * g];
    bf8 kb1 = *(const bf8*)&kbase[(16 + cc) * 64 + 32 + 8 * g];
    const short* vp0 = vbase + g * 512 + cc * 8;
    bf8 vv0 = *(const bf8*)&vp0[0];
    bf8 vv1 = *(const bf8*)&vp0[128];
    bf8 vv2 = *(const bf8*)&vp0[256];
    bf8 vv3 = *(const bf8*)&vp0[384];

    for (int t = 0; t < NT; ++t) {
        const int sn = (t + 1 < NT) ? t + 1 : 0;   // wrap: harmless redundant load
        const short* kn = kbase + sn * 2048;
        const bf8 nka0 = *(const bf8*)&kn[cc * 64 + 8 * g];
        const bf8 nka1 = *(const bf8*)&kn[cc * 64 + 32 + 8 * g];
        const bf8 nkb0 = *(const bf8*)&kn[(16 + cc) * 64 + 8 * g];
        const bf8 nkb1 = *(const bf8*)&kn[(16 + cc) * 64 + 32 + 8 * g];
        const short* vn = vbase + sn * 2048 + g * 512 + cc * 8;
        const bf8 nv0 = *(const bf8*)&vn[0];
        const bf8 nv1 = *(const bf8*)&vn[128];
        const bf8 nv2 = *(const bf8*)&vn[256];
        const bf8 nv3 = *(const bf8*)&vn[384];

        __builtin_amdgcn_s_setprio(1);
        f4 sA = (f4){0.f, 0.f, 0.f, 0.f};
        sA = mfma16(ka0, qf0, sA);
        sA = mfma16(ka1, qf1, sA);    // lane: S[q=cc][k-row 4g+r] (log2 domain)
        f4 sB = (f4){0.f, 0.f, 0.f, 0.f};
        sB = mfma16(kb0, qf0, sB);
        sB = mfma16(kb1, qf1, sB);    // rows 16+4g+r
        __builtin_amdgcn_s_setprio(0);

        // per-lane max of this lane's 8 slices; __all over the wave covers all
        // 4 k-slice groups of each q -> no cross-lane reduce in the common path
        const float tm = fmaxf(fmaxf(fmaxf(sA[0], sA[1]), fmaxf(sA[2], sA[3])),
                               fmaxf(fmaxf(sB[0], sB[1]), fmaxf(sB[2], sB[3])));
        if (!__all(tm <= mrun + 8.f)) {    // defer-max (log2 units): P <= 2^8
            float tmx = fmaxf(tm, __shfl_xor(tm, 16));
            tmx = fmaxf(tmx, __shfl_xor(tmx, 32));   // true per-q max
            const float mnew = fmaxf(mrun, tmx);
            const float corr = EXP2F(mrun - mnew);   // first iter: 2^-inf = 0
            sl *= corr;
#pragma unroll
            for (int r = 0; r < 4; ++r) {            // O rows q=4g+r
                const float cr = __shfl(corr, 4 * g + r);
                O[0][r] *= cr; O[1][r] *= cr; O[2][r] *= cr; O[3][r] *= cr;
            }
            mrun = mnew;
        }

        float p[8];
#pragma unroll
        for (int r = 0; r < 4; ++r) { p[r] = EXP2F(sA[r] - mrun); sl += p[r]; }
#pragma unroll
        for (int r = 0; r < 4; ++r) { p[4 + r] = EXP2F(sB[r] - mrun); sl += p[4 + r]; }

        bf8 pf;
#pragma unroll
        for (int jj = 0; jj < 8; ++jj) pf[jj] = f2b(p[jj]);
        __builtin_amdgcn_s_setprio(1);
        O[0] = mfma16(pf, vv0, O[0]);
        O[1] = mfma16(pf, vv1, O[1]);
        O[2] = mfma16(pf, vv2, O[2]);
        O[3] = mfma16(pf, vv3, O[3]);
        __builtin_amdgcn_s_setprio(0);

        ka0 = nka0; ka1 = nka1; kb0 = nkb0; kb1 = nkb1;
        vv0 = nv0; vv1 = nv1; vv2 = nv2; vv3 = nv3;
    }

    // reduce per-lane partial sums across the 4 k-slice groups -> per-q total
    float stot = sl;
    stot += __shfl_xor(stot, 16);
    stot += __shfl_xor(stot, 32);

    if (SPLIT) {
        if (lane < 16)   // g==0 lanes: q = q0 + cc
            ms[kh * 65536 + bh * 2048 + q0 + cc] = make_float2(mrun, stot);
        short* op = opart + kh * 4194304;
#pragma unroll
        for (int nb = 0; nb < 4; ++nb)
#pragma unroll
            for (int r = 0; r < 4; ++r)
                op[(bh * 2048 + q0 + 4 * g + r) * 64 + 16 * nb + cc] = f2b(O[nb][r]);
    } else {
        const int b_ = bh >> 4, h = bh & 15;
        const float inv = 1.0f / stot;
        float ir[4];
#pragma unroll
        for (int r = 0; r < 4; ++r) ir[r] = __shfl(inv, 4 * g + r);
#pragma unroll
        for (int nb = 0; nb < 4; ++nb)
#pragma unroll
            for (int r = 0; r < 4; ++r)
                atb[(b_ * 2048 + q0 + 4 * g + r) * 1024 + h * 64 + 16 * nb + cc] =
                    f2b(O[nb][r] * ir[r]);
    }
}

// ---------- split-K combine: atb = (O0*w0 + O1*w1) / (s0*w0 + s1*w1) ----------
__global__ __launch_bounds__(256) void comb_k(const short* __restrict__ opart,
                                              const float2* __restrict__ ms,
                                              short* __restrict__ atb) {
    const int gi = blockIdx.x * 256 + threadIdx.x;   // 524288 threads
    const int row = gi >> 3;                          // bh*2048 + q
    const int d0 = (gi & 7) * 8;
    const float2 a = ms[row], b = ms[65536 + row];
    const float mm = fmaxf(a.x, b.x);
    const float w0 = EXP2F(a.x - mm);
    const float w1 = EXP2F(b.x - mm);
    const float inv = 1.f / (a.y * w0 + b.y * w1);
    const bf8 o0 = *(const bf8*)&opart[row * 64 + d0];
    const bf8 o1 = *(const bf8*)&opart[4194304 + row * 64 + d0];
    const int bh = row >> 11, q = row & 2047;
    const int b_ = bh >> 4, h = bh & 15;
    bf8 o;
#pragma unroll
    for (int j = 0; j < 8; ++j)
        o[j] = f2b((b2f(o0[j]) * w0 + b2f(o1[j]) * w1) * inv);
    *(bf8*)&atb[(b_ * 2048 + q) * 1024 + h * 64 + d0] = o;
}

// ---------- launch ----------
extern "C" void kernel_launch(void* const* d_in, const int* in_sizes, int n_in,
                              void* d_out, int out_size, void* d_ws, size_t ws_size,
                              hipStream_t stream) {
    const float* x  = (const float*)d_in[0];
    const int*   dt = (const int*)d_in[1];
    const float* Wq = (const float*)d_in[2];
    const float* bq = (const float*)d_in[3];
    const float* Wk = (const float*)d_in[4];
    const float* bk = (const float*)d_in[5];
    const float* Wv = (const float*)d_in[6];
    const float* bv = (const float*)d_in[7];
    const float* Wo = (const float*)d_in[8];
    const float* bo = (const float*)d_in[9];

    float* out   = (float*)d_out;          // (M,1024)
    float* out_k = out + 4194304;          // (B,H,L,64)
    float* out_v = out + 8388608;

    short* xb   = (short*)d_ws;            // bf16 x
    short* wqb  = xb + 4194304;            // stacked [Wq;Wk;Wv] bf16 (contiguous)
    short* wkb  = wqb + 1048576;
    short* wvb  = wkb + 1048576;
    short* wob  = wvb + 1048576;
    short* qrot = wob + 1048576;
    short* kbb  = qrot + 4194304;
    short* vpk  = kbb + 4194304;
    short* atb  = vpk + 4194304;
    float* ctab = (float*)(atb + 4194304);
    float* stab = ctab + 512;
    short* opart = (short*)(stab + 512);   // 2 x (32,2048,64) bf16 = 16 MB
    float2* ms   = (float2*)(opart + 8388608);  // 2 x 65536 float2 = 1 MB

    const size_t need = (size_t)((short*)(ms + 131072) - (short*)d_ws) * sizeof(short);
    const bool split = ws_size >= need;

    conv_k<<<8193, 256, 0, stream>>>(x, Wq, Wk, Wv, Wo, dt,
                                     xb, wqb, wkb, wvb, wob, ctab, stab);
    gemm_qkv_k<<<dim3(24, 32), 256, 0, stream>>>(xb, wqb, bq, bk, bv,
                                                 out_k, out_v, qrot, kbb, vpk, ctab, stab);
    if (split) {
        attn_k<1><<<2048, 256, 0, stream>>>(qrot, kbb, vpk, atb, opart, ms);
        comb_k<<<2048, 256, 0, stream>>>(opart, ms, atb);
    } else {
        attn_k<0><<<1024, 256, 0, stream>>>(qrot, kbb, vpk, atb, nullptr, nullptr);
    }
    gemm_o_k<<<dim3(16, 32), 256, 0, stream>>>(atb, wob, bo, out);
}

// Round 4
// 208.581 us; speedup vs baseline: 1.7224x; 1.4761x over previous
//
#include <hip/hip_runtime.h>

// ---------- types ----------
typedef short bf8 __attribute__((ext_vector_type(8)));   // 8 bf16 bit-patterns (4 VGPR)
typedef short s4v __attribute__((ext_vector_type(4)));
typedef float f4  __attribute__((ext_vector_type(4)));

// Sizes fixed: B=2, NT=16, LD=128 -> L=2048, M=4096, D=1024, H=16, Hd=64

__device__ __forceinline__ short f2b(float f) {          // fp32 -> bf16 (RNE)
    unsigned u = __float_as_uint(f);
    u += 0x7FFFu + ((u >> 16) & 1u);
    return (short)(u >> 16);
}

__device__ __forceinline__ f4 mfma16(bf8 a, bf8 b, f4 c) {
    return __builtin_amdgcn_mfma_f32_16x16x32_bf16(a, b, c, 0, 0, 0);
}

__device__ __forceinline__ void gl_lds16(const short* g, short* l) {
    __builtin_amdgcn_global_load_lds(
        (const __attribute__((address_space(1))) void*)g,
        (__attribute__((address_space(3))) void*)l, 16, 0, 0);
}

#define EXP2F(x) __builtin_amdgcn_exp2f(x)

// ---------- fused converts: x + 4 weights -> bf16, plus RoPE table ----------
__global__ __launch_bounds__(256) void conv_k(
    const float* __restrict__ x, const float* __restrict__ wq,
    const float* __restrict__ wk, const float* __restrict__ wv,
    const float* __restrict__ wo, const int* __restrict__ dt,
    short* __restrict__ xb, short* __restrict__ wqb, short* __restrict__ wkb,
    short* __restrict__ wvb, short* __restrict__ wob,
    float* __restrict__ ctab, float* __restrict__ stab) {
    if (blockIdx.x == 8192) {   // RoPE cos/sin table: [16 t][32 freqs]
        const int tid = threadIdx.x;
        const int ii = tid & 31;
        const float invf = exp2f(-(float)ii * (16.609640474436812f / 32.f)); // 1e5^(-i/32)
        for (int t = tid >> 5; t < 16; t += 8) {
            const float a = (float)dt[t] * invf;
            ctab[t * 32 + ii] = cosf(a);
            stab[t * 32 + ii] = sinf(a);
        }
        return;
    }
    int idx = (blockIdx.x * 256 + threadIdx.x) * 4;
    const float* s; short* d; int off = idx;
    if (idx < 4194304)      { s = x;  d = xb; }
    else if (idx < 5242880) { s = wq; d = wqb; off = idx - 4194304; }
    else if (idx < 6291456) { s = wk; d = wkb; off = idx - 5242880; }
    else if (idx < 7340032) { s = wv; d = wvb; off = idx - 6291456; }
    else                    { s = wo; d = wob; off = idx - 7340032; }
    const float4 v = *(const float4*)&s[off];
    s4v o;
    o[0] = f2b(v.x); o[1] = f2b(v.y); o[2] = f2b(v.z); o[3] = f2b(v.w);
    *(s4v*)&d[off] = o;
}

// ---------- fused QKV GEMM: C[4096 x 3072] = x @ [Wq;Wk;Wv]^T + b, fused epilogues ----------
// third 0 = Q (RoPE, *0.125*log2e -> bf16 qrot), 1 = K (RoPE -> fp32 out_k + bf16 kbb,
// kbb stored per-32-row tile with XOR bank swizzle), 2 = V (fp32 out_v + bf16 vpk packed)
__global__ __launch_bounds__(256) void gemm_qkv_k(
    const short* __restrict__ A, const short* __restrict__ W,
    const float* __restrict__ bq, const float* __restrict__ bk, const float* __restrict__ bv,
    float* __restrict__ out_k, float* __restrict__ out_v,
    short* __restrict__ qrot, short* __restrict__ kbb, short* __restrict__ vpk,
    const float* __restrict__ ctab, const float* __restrict__ stab) {
    __shared__ __align__(16) short As[128 * 32];   // linear, for global_load_lds
    __shared__ __align__(16) short Bs[128 * 32];

    const int n0f = blockIdx.x * 128;              // 0..2944
    const int m0 = blockIdx.y * 128;
    const int tid = threadIdx.x;
    const int lane = tid & 63;
    const int w = tid >> 6;
    const int wr = w >> 1, wc = w & 1;
    const int g = lane >> 4, cc = lane & 15;

    const int c0 = w * 128 + lane;
    const int ar0 = c0 >> 2, ap0 = (c0 & 3) * 8;
    const short* Ag0 = A + (m0 + ar0) * 1024 + ap0;
    const short* Ag1 = Ag0 + 16 * 1024;
    const short* Wg0 = W + (n0f + ar0) * 1024 + ap0;
    const short* Wg1 = Wg0 + 16 * 1024;
    short* lA0 = &As[w * 1024];
    short* lA1 = &As[w * 1024 + 512];
    short* lB0 = &Bs[w * 1024];
    short* lB1 = &Bs[w * 1024 + 512];

    f4 acc[4][4];
#pragma unroll
    for (int i = 0; i < 4; ++i)
#pragma unroll
        for (int j = 0; j < 4; ++j) acc[i][j] = (f4){0.f, 0.f, 0.f, 0.f};

    for (int k0 = 0; k0 < 1024; k0 += 32) {
        gl_lds16(Ag0 + k0, lA0);
        gl_lds16(Ag1 + k0, lA1);
        gl_lds16(Wg0 + k0, lB0);
        gl_lds16(Wg1 + k0, lB1);
        __syncthreads();
        bf8 af[4], bfr[4];
#pragma unroll
        for (int fm = 0; fm < 4; ++fm)
            af[fm] = *(const bf8*)&As[(64 * wr + 16 * fm + cc) * 32 + 8 * g];
#pragma unroll
        for (int fn = 0; fn < 4; ++fn)
            bfr[fn] = *(const bf8*)&Bs[(64 * wc + 16 * fn + cc) * 32 + 8 * g];
#pragma unroll
        for (int fm = 0; fm < 4; ++fm)
#pragma unroll
            for (int fn = 0; fn < 4; ++fn)
                acc[fm][fn] = mfma16(af[fm], bfr[fn], acc[fm][fn]);
        __syncthreads();
    }

    const int third = n0f >> 10;
    const int n0 = n0f & 1023;
    const int h = (n0 + 64 * wc) >> 6;
    const float* bias = (third == 0) ? bq : ((third == 1) ? bk : bv);

#pragma unroll
    for (int fm = 0; fm < 4; ++fm) {
#pragma unroll
        for (int r = 0; r < 4; ++r) {
            const int m = m0 + 64 * wr + 16 * fm + 4 * g + r;
            const int b_ = m >> 11, l = m & 2047;
            const int bh2 = b_ * 16 + h;
            if (third == 2) {   // V: fp32 out + PV-fragment pack (per-tile contiguous 4KB)
                const int st2 = l >> 5, s = l & 31;
                const int j = 4 * (s >> 4) + (s & 3);
                const int g2 = (s >> 2) & 3;
#pragma unroll
                for (int fn = 0; fn < 4; ++fn) {
                    const int d = 16 * fn + cc;
                    const int n = n0 + 64 * wc + 16 * fn + cc;
                    const float val = acc[fm][fn][r] + bias[n];
                    out_v[(bh2 * 2048 + l) * 64 + d] = val;
                    const int vp = (((bh2 * 64 + st2) * 4 + g2) * 4 + (d >> 4)) * 128 + (d & 15) * 8 + j;
                    vpk[vp] = f2b(val);
                }
            } else {            // Q or K: RoPE pairs (fn, fn+2) = (d, d+32), same lane
                const int tt = l >> 7;
#pragma unroll
                for (int fn = 0; fn < 2; ++fn) {
                    const int d1 = 16 * fn + cc;
                    const int n1 = n0 + 64 * wc + d1;
                    const float v1 = acc[fm][fn][r] + bias[n1];
                    const float v2 = acc[fm][fn + 2][r] + bias[n1 + 32];
                    const float ct = ctab[tt * 32 + d1];
                    const float sn = stab[tt * 32 + d1];
                    const float r1 = v1 * ct - v2 * sn;
                    const float r2 = v2 * ct + v1 * sn;
                    const int oi = (bh2 * 2048 + l) * 64 + d1;
                    if (third == 0) {
                        // fold 1/sqrt(64) * log2(e): softmax runs in exp2 domain
                        qrot[oi]      = f2b(r1 * 0.18033688011f);
                        qrot[oi + 32] = f2b(r2 * 0.18033688011f);
                    } else {
                        out_k[oi] = r1; out_k[oi + 32] = r2;
                        // swizzled tile layout: byte = (kr*128 + d*2) ^ ((kr&7)<<4)
                        const int kr = l & 31, tl = l >> 5;
                        const int kb_ = bh2 * 131072 + tl * 2048;
                        kbb[kb_ + (((kr * 128 + d1 * 2) ^ ((kr & 7) << 4)) >> 1)] = f2b(r1);
                        kbb[kb_ + (((kr * 128 + (d1 + 32) * 2) ^ ((kr & 7) << 4)) >> 1)] = f2b(r2);
                    }
                }
            }
        }
    }
}

// ---------- Wo GEMM: out[4096x1024] = atb @ Wo^T + bo ; BM=128 BN=64 ----------
__global__ __launch_bounds__(256) void gemm_o_k(
    const short* __restrict__ A, const short* __restrict__ W,
    const float* __restrict__ bias, float* __restrict__ out) {
    __shared__ __align__(16) short As[128 * 32];
    __shared__ __align__(16) short Bs[64 * 32];

    const int n0 = blockIdx.x * 64;
    const int m0 = blockIdx.y * 128;
    const int tid = threadIdx.x;
    const int lane = tid & 63;
    const int w = tid >> 6;
    const int wr = w >> 1, wc = w & 1;   // wave tile: 64 x 32
    const int g = lane >> 4, cc = lane & 15;

    const int c0 = w * 128 + lane;
    const int ar0 = c0 >> 2, ap0 = (c0 & 3) * 8;
    const short* Ag0 = A + (m0 + ar0) * 1024 + ap0;
    const short* Ag1 = Ag0 + 16 * 1024;
    const int cb = w * 64 + lane;
    const short* Wg0 = W + (n0 + (cb >> 2)) * 1024 + (cb & 3) * 8;
    short* lA0 = &As[w * 1024];
    short* lA1 = &As[w * 1024 + 512];
    short* lB0 = &Bs[w * 512];

    f4 acc[4][2];
#pragma unroll
    for (int i = 0; i < 4; ++i) { acc[i][0] = (f4){0,0,0,0}; acc[i][1] = (f4){0,0,0,0}; }

    for (int k0 = 0; k0 < 1024; k0 += 32) {
        gl_lds16(Ag0 + k0, lA0);
        gl_lds16(Ag1 + k0, lA1);
        gl_lds16(Wg0 + k0, lB0);
        __syncthreads();
        bf8 af[4], bfr[2];
#pragma unroll
        for (int fm = 0; fm < 4; ++fm)
            af[fm] = *(const bf8*)&As[(64 * wr + 16 * fm + cc) * 32 + 8 * g];
#pragma unroll
        for (int fn = 0; fn < 2; ++fn)
            bfr[fn] = *(const bf8*)&Bs[(32 * wc + 16 * fn + cc) * 32 + 8 * g];
#pragma unroll
        for (int fm = 0; fm < 4; ++fm)
#pragma unroll
            for (int fn = 0; fn < 2; ++fn)
                acc[fm][fn] = mfma16(af[fm], bfr[fn], acc[fm][fn]);
        __syncthreads();
    }
#pragma unroll
    for (int fm = 0; fm < 4; ++fm)
#pragma unroll
        for (int r = 0; r < 4; ++r) {
            const int m = m0 + 64 * wr + 16 * fm + 4 * g + r;
#pragma unroll
            for (int fn = 0; fn < 2; ++fn) {
                const int n = n0 + 32 * wc + 16 * fn + cc;
                out[m * 1024 + n] = acc[fm][fn][r] + bias[n];
            }
        }
}

// ---------- flash attention: block-cooperative, LDS-staged K/V, 8 waves x 32 q ----------
// 256 blocks (1/CU): 32 bh x 8 q-chunks of 256 rows. K/V tiles (32 k-rows) staged once
// per block via global_load_lds, double-buffered; all 8 waves share them from LDS.
__global__ __launch_bounds__(512, 2) void attn_k(
    const short* __restrict__ q_rot, const short* __restrict__ k_b,
    const short* __restrict__ v_pk, short* __restrict__ atb) {
    __shared__ __align__(16) short lds[8192];   // 2 buffers x (4KB K + 4KB V)

    const int i = blockIdx.x;
    const int xcd = i & 7, slot = i >> 3;       // 4 bh per XCD -> K/V fits per-XCD L2
    const int bh = xcd + 8 * (slot & 3);
    const int qc = slot >> 2;                   // 0..7
    const int tid = threadIdx.x;
    const int lane = tid & 63;
    const int w = tid >> 6;                     // 0..7
    const int g = lane >> 4, cc = lane & 15;
    const int b_ = bh >> 4, h = bh & 15;
    const int q0w = qc * 256 + w * 32;

    // Q fragments (B-operand): lane(g,cc) holds Q[q = qt*16+cc][d = half*32 + 8g+j]
    const short* qp = q_rot + (bh * 2048 + q0w) * 64;
    const bf8 qf00 = *(const bf8*)&qp[cc * 64 + 8 * g];
    const bf8 qf01 = *(const bf8*)&qp[cc * 64 + 32 + 8 * g];
    const bf8 qf10 = *(const bf8*)&qp[(16 + cc) * 64 + 8 * g];
    const bf8 qf11 = *(const bf8*)&qp[(16 + cc) * 64 + 32 + 8 * g];

    // staging: waves 0-3 stage K (4KB), waves 4-7 stage V (4KB); 16B per lane
    const int part = w >> 2, sub = w & 3;
    const short* gsrc = (part ? v_pk : k_b) + bh * 131072 + sub * 512 + lane * 8;
    const int lofs = part * 2048 + sub * 512;   // shorts, within one 8KB buffer

    // per-lane K read offsets (bytes), XOR bank swizzle matches GEMM's kbb layout
    const int swz = (cc & 7) << 4;
    const int koA0 = (cc * 128 + g * 16) ^ swz;
    const int koA1 = (cc * 128 + 64 + g * 16) ^ swz;
    const int koB0 = ((16 + cc) * 128 + g * 16) ^ swz;
    const int koB1 = ((16 + cc) * 128 + 64 + g * 16) ^ swz;
    const int vo = 4096 + g * 1024 + cc * 16;   // bytes (V region), bank-uniform as-is

    f4 O0[4], O1[4], Os0, Os1;
#pragma unroll
    for (int nb = 0; nb < 4; ++nb) { O0[nb] = (f4){0,0,0,0}; O1[nb] = (f4){0,0,0,0}; }
    Os0 = (f4){0,0,0,0}; Os1 = (f4){0,0,0,0};
    float m0 = -INFINITY, m1 = -INFINITY;       // per-q (cc) running max, log2 domain

    bf8 ONES;
#pragma unroll
    for (int j = 0; j < 8; ++j) ONES[j] = (short)0x3F80;   // bf16 1.0

    // prologue: stage tile 0 -> buf 0
    gl_lds16(gsrc, lds + lofs);
    asm volatile("s_waitcnt vmcnt(0)" ::: "memory");
    __builtin_amdgcn_s_barrier();

    int cur = 0;
    for (int t = 0; t < 64; ++t) {
        if (t < 63)
            gl_lds16(gsrc + (t + 1) * 2048, lds + ((cur ^ 1) * 4096 + lofs));
        const char* buf = (const char*)lds + cur * 8192;

        const bf8 ka0 = *(const bf8*)(buf + koA0);
        const bf8 ka1 = *(const bf8*)(buf + koA1);
        const bf8 kb0 = *(const bf8*)(buf + koB0);
        const bf8 kb1 = *(const bf8*)(buf + koB1);
        const bf8 vv0 = *(const bf8*)(buf + vo);
        const bf8 vv1 = *(const bf8*)(buf + vo + 256);
        const bf8 vv2 = *(const bf8*)(buf + vo + 512);
        const bf8 vv3 = *(const bf8*)(buf + vo + 768);

        __builtin_amdgcn_s_setprio(1);
        f4 sA0 = (f4){0,0,0,0}, sB0 = (f4){0,0,0,0};
        f4 sA1 = (f4){0,0,0,0}, sB1 = (f4){0,0,0,0};
        sA0 = mfma16(ka0, qf00, sA0); sA0 = mfma16(ka1, qf01, sA0);
        sB0 = mfma16(kb0, qf00, sB0); sB0 = mfma16(kb1, qf01, sB0);
        sA1 = mfma16(ka0, qf10, sA1); sA1 = mfma16(ka1, qf11, sA1);
        sB1 = mfma16(kb0, qf10, sB1); sB1 = mfma16(kb1, qf11, sB1);
        __builtin_amdgcn_s_setprio(0);
        // lane(g,cc) reg r: S[q=qt*16+cc][k = 4g+r (A) / 16+4g+r (B)]

        const float t0 = fmaxf(fmaxf(fmaxf(sA0[0], sA0[1]), fmaxf(sA0[2], sA0[3])),
                               fmaxf(fmaxf(sB0[0], sB0[1]), fmaxf(sB0[2], sB0[3])));
        const float t1 = fmaxf(fmaxf(fmaxf(sA1[0], sA1[1]), fmaxf(sA1[2], sA1[3])),
                               fmaxf(fmaxf(sB1[0], sB1[1]), fmaxf(sB1[2], sB1[3])));
        if (!__all(t0 <= m0 + 8.f && t1 <= m1 + 8.f)) {   // defer-max: P <= 2^8
            float x0 = fmaxf(t0, __shfl_xor(t0, 16)); x0 = fmaxf(x0, __shfl_xor(x0, 32));
            float x1 = fmaxf(t1, __shfl_xor(t1, 16)); x1 = fmaxf(x1, __shfl_xor(x1, 32));
            const float n0 = fmaxf(m0, x0), n1 = fmaxf(m1, x1);
            const float c0 = EXP2F(m0 - n0), c1 = EXP2F(m1 - n1);  // first iter: 0
#pragma unroll
            for (int r = 0; r < 4; ++r) {                 // O rows are q = 4g+r
                const float cr0 = __shfl(c0, 4 * g + r);
                const float cr1 = __shfl(c1, 4 * g + r);
                O0[0][r] *= cr0; O0[1][r] *= cr0; O0[2][r] *= cr0; O0[3][r] *= cr0;
                Os0[r] *= cr0;
                O1[0][r] *= cr1; O1[1][r] *= cr1; O1[2][r] *= cr1; O1[3][r] *= cr1;
                Os1[r] *= cr1;
            }
            m0 = n0; m1 = n1;
        }

        // P = exp2(S - m), packed to bf16 by truncation (Osum uses same P -> bias cancels)
        union { bf8 v; unsigned u[4]; } P0, P1;
        {
            float p[8];
#pragma unroll
            for (int r = 0; r < 4; ++r) { p[r] = EXP2F(sA0[r] - m0); p[4 + r] = EXP2F(sB0[r] - m0); }
#pragma unroll
            for (int k2 = 0; k2 < 4; ++k2)
                P0.u[k2] = (__float_as_uint(p[2 * k2]) >> 16) |
                           (__float_as_uint(p[2 * k2 + 1]) & 0xFFFF0000u);
        }
        {
            float p[8];
#pragma unroll
            for (int r = 0; r < 4; ++r) { p[r] = EXP2F(sA1[r] - m1); p[4 + r] = EXP2F(sB1[r] - m1); }
#pragma unroll
            for (int k2 = 0; k2 < 4; ++k2)
                P1.u[k2] = (__float_as_uint(p[2 * k2]) >> 16) |
                           (__float_as_uint(p[2 * k2 + 1]) & 0xFFFF0000u);
        }

        __builtin_amdgcn_s_setprio(1);
        O0[0] = mfma16(P0.v, vv0, O0[0]); O0[1] = mfma16(P0.v, vv1, O0[1]);
        O0[2] = mfma16(P0.v, vv2, O0[2]); O0[3] = mfma16(P0.v, vv3, O0[3]);
        Os0 = mfma16(P0.v, ONES, Os0);    // row-sums, same lane/reg layout as O rows
        O1[0] = mfma16(P1.v, vv0, O1[0]); O1[1] = mfma16(P1.v, vv1, O1[1]);
        O1[2] = mfma16(P1.v, vv2, O1[2]); O1[3] = mfma16(P1.v, vv3, O1[3]);
        Os1 = mfma16(P1.v, ONES, Os1);
        __builtin_amdgcn_s_setprio(0);

        asm volatile("s_waitcnt vmcnt(0)" ::: "memory");  // drain this iter's stage
        __builtin_amdgcn_s_barrier();
        cur ^= 1;
    }

    short* ob = atb + (b_ * 2048 + q0w) * 1024 + h * 64 + cc;
#pragma unroll
    for (int r = 0; r < 4; ++r) {
        const float i0 = 1.f / Os0[r];
        const float i1 = 1.f / Os1[r];
#pragma unroll
        for (int nb = 0; nb < 4; ++nb) {
            ob[(4 * g + r) * 1024 + nb * 16]        = f2b(O0[nb][r] * i0);
            ob[(16 + 4 * g + r) * 1024 + nb * 16]   = f2b(O1[nb][r] * i1);
        }
    }
}

// ---------- launch ----------
extern "C" void kernel_launch(void* const* d_in, const int* in_sizes, int n_in,
                              void* d_out, int out_size, void* d_ws, size_t ws_size,
                              hipStream_t stream) {
    const float* x  = (const float*)d_in[0];
    const int*   dt = (const int*)d_in[1];
    const float* Wq = (const float*)d_in[2];
    const float* bq = (const float*)d_in[3];
    const float* Wk = (const float*)d_in[4];
    const float* bk = (const float*)d_in[5];
    const float* Wv = (const float*)d_in[6];
    const float* bv = (const float*)d_in[7];
    const float* Wo = (const float*)d_in[8];
    const float* bo = (const float*)d_in[9];

    float* out   = (float*)d_out;          // (M,1024)
    float* out_k = out + 4194304;          // (B,H,L,64)
    float* out_v = out + 8388608;

    short* xb   = (short*)d_ws;            // bf16 x
    short* wqb  = xb + 4194304;            // stacked [Wq;Wk;Wv] bf16 (contiguous)
    short* wkb  = wqb + 1048576;
    short* wvb  = wkb + 1048576;
    short* wob  = wvb + 1048576;
    short* qrot = wob + 1048576;
    short* kbb  = qrot + 4194304;          // K bf16, swizzled 4KB tiles
    short* vpk  = kbb + 4194304;           // V bf16, packed 4KB tiles
    short* atb  = vpk + 4194304;
    float* ctab = (float*)(atb + 4194304);
    float* stab = ctab + 512;

    conv_k<<<8193, 256, 0, stream>>>(x, Wq, Wk, Wv, Wo, dt,
                                     xb, wqb, wkb, wvb, wob, ctab, stab);
    gemm_qkv_k<<<dim3(24, 32), 256, 0, stream>>>(xb, wqb, bq, bk, bv,
                                                 out_k, out_v, qrot, kbb, vpk, ctab, stab);
    attn_k<<<256, 512, 0, stream>>>(qrot, kbb, vpk, atb);
    gemm_o_k<<<dim3(16, 32), 256, 0, stream>>>(atb, wob, bo, out);
}